// Round 12
// baseline (376.282 us; speedup 1.0000x reference)
//
#include <hip/hip_runtime.h>
#include <math.h>

#define LRELU(v) ((v) > 0.0f ? (v) : 0.2f * (v))

typedef __bf16 bf16x8 __attribute__((ext_vector_type(8)));
typedef float f32x4 __attribute__((ext_vector_type(4)));
typedef float f32x2 __attribute__((ext_vector_type(2)));

__device__ __forceinline__ unsigned short f2bf(float f) {
    unsigned int u = __float_as_uint(f);
    u += 0x7FFF + ((u >> 16) & 1);
    return (unsigned short)(u >> 16);
}
__device__ __forceinline__ float bf2f(unsigned short s) {
    return __uint_as_float(((unsigned int)s) << 16);
}

// ---------------- prep: W1T cast + W2T cast + hist/rank ----------------
__global__ __launch_bounds__(256) void prep_k(const float* __restrict__ W1, unsigned short* __restrict__ W1T,
                                              const float* __restrict__ W2, unsigned short* __restrict__ W2T,
                                              const int* __restrict__ edge, int* __restrict__ cnt,
                                              int* __restrict__ rank, int E) {
    int b = blockIdx.x;
    if (b < 256) {
        int i = b * 256 + threadIdx.x;
        int k = i >> 8, n = i & 255;
        W1T[(size_t)n * 256 + k] = f2bf(W1[i]);
    } else if (b < 320) {
        int i = (b - 256) * 256 + threadIdx.x;
        int k = i >> 6, n = i & 63;
        W2T[(size_t)n * 256 + k] = f2bf(W2[i]);
    } else {
        int i = (b - 320) * 256 + threadIdx.x;
        if (i < E) rank[i] = atomicAdd(&cnt[edge[E + i]], 1);
    }
}

// ---------------- scan hierarchy ----------------
__global__ __launch_bounds__(256) void psum_k(const int* __restrict__ cnt, int* __restrict__ bsum, int N) {
    __shared__ int wsh[4];
    int b = blockIdx.x;
    int gi = b * 1024 + threadIdx.x * 4;
    int s = 0;
    if (gi + 3 < N) {
        int4 v = *(const int4*)(cnt + gi);
        s = v.x + v.y + v.z + v.w + 4;
    } else {
        for (int j = 0; j < 4; ++j) if (gi + j < N) s += cnt[gi + j] + 1;
    }
#pragma unroll
    for (int off = 1; off < 64; off <<= 1) s += __shfl_xor(s, off, 64);
    if ((threadIdx.x & 63) == 0) wsh[threadIdx.x >> 6] = s;
    __syncthreads();
    if (threadIdx.x == 0) bsum[b] = wsh[0] + wsh[1] + wsh[2] + wsh[3];
}

__global__ void bscan_k(int* __restrict__ bsum, int B) {
    __shared__ int sh[128];
    int t = threadIdx.x;
    int v = (t < B) ? bsum[t] : 0;
    sh[t] = v;
    __syncthreads();
    for (int off = 1; off < 128; off <<= 1) {
        int u = (t >= off) ? sh[t - off] : 0;
        __syncthreads();
        sh[t] += u;
        __syncthreads();
    }
    if (t < B) bsum[t] = sh[t] - v;  // exclusive prefix
}

__global__ __launch_bounds__(256) void rowptr_k(const int* __restrict__ cnt, const int* __restrict__ bsum,
                                                int* __restrict__ row_ptr, int N) {
    __shared__ int wsh[4];
    int b = blockIdx.x;
    int t = threadIdx.x;
    int gi = b * 1024 + t * 4;
    int c[4];
    int s = 0;
#pragma unroll
    for (int j = 0; j < 4; ++j) {
        int i = gi + j;
        c[j] = (i < N) ? cnt[i] + 1 : 0;
        s += c[j];
    }
    int lane = t & 63, w = t >> 6;
    int ps = s;
#pragma unroll
    for (int off = 1; off < 64; off <<= 1) {
        int u = __shfl_up(ps, off, 64);
        if (lane >= off) ps += u;
    }
    if (lane == 63) wsh[w] = ps;
    __syncthreads();
    int wbase = 0;
    for (int k = 0; k < w; ++k) wbase += wsh[k];
    int base = bsum[b] + wbase + (ps - s);
#pragma unroll
    for (int j = 0; j < 4; ++j) {
        int i = gi + j;
        if (i < N) row_ptr[i] = base;
        base += c[j];
    }
    if (N - 1 >= gi && N - 1 < gi + 4) row_ptr[N] = base;
}

// ---------------- counting-sort placement (no atomics) ----------------
__global__ void scatter_k(const int* __restrict__ edge, const int* __restrict__ row_ptr,
                          const int* __restrict__ rank, int* __restrict__ col, int E, int N) {
    int i = blockIdx.x * blockDim.x + threadIdx.x;
    if (i < E) {
        int dst = edge[E + i];
        col[row_ptr[dst] + rank[i]] = edge[i];
    } else if (i < E + N) {
        int n = i - E;
        col[row_ptr[n + 1] - 1] = n;    // self-loop in last slot
    }
}

// ---------------- gemm1: fp8 Q = f32 A @ BT^T, dots1 fused into epilogue ----------------
__global__ __launch_bounds__(256) void gemm1f_k(const float* __restrict__ A,
                                                const unsigned short* __restrict__ BT,
                                                const float* __restrict__ AS1, const float* __restrict__ AD1,
                                                unsigned char* __restrict__ Q,
                                                float* __restrict__ es1, float* __restrict__ ed1, int M) {
    constexpr int K = 256, BM = 128, BK = 32;
    __shared__ char As[BM * 80];
    __shared__ char Bs[256 * 80];
    __shared__ float sa[256], sd_[256];
    int tid = threadIdx.x;
    sa[tid] = AS1[tid];
    sd_[tid] = AD1[tid];
    int m0 = blockIdx.x * BM;
    int wid = tid >> 6, lane = tid & 63;
    int wm = (wid >> 1) * 64, wn = (wid & 1) * 128;
    int l15 = lane & 15, g = lane >> 4;
    f32x4 acc[4][8] = {};

    for (int k0 = 0; k0 < K; k0 += BK) {
#pragma unroll
        for (int i = 0; i < 2; ++i) {
            int c = tid + i * 256;
            int r = c >> 2, kc = c & 3;
            int gm = m0 + r; if (gm >= M) gm = M - 1;
            const float* src = A + (size_t)gm * K + k0 + kc * 8;
            float4 v0 = *(const float4*)(src);
            float4 v1 = *(const float4*)(src + 4);
            uint4 pk;
            pk.x = f2bf(v0.x) | ((unsigned)f2bf(v0.y) << 16);
            pk.y = f2bf(v0.z) | ((unsigned)f2bf(v0.w) << 16);
            pk.z = f2bf(v1.x) | ((unsigned)f2bf(v1.y) << 16);
            pk.w = f2bf(v1.z) | ((unsigned)f2bf(v1.w) << 16);
            *(uint4*)(As + r * 80 + kc * 16) = pk;
        }
#pragma unroll
        for (int i = 0; i < 4; ++i) {
            int c = tid + i * 256;
            int r = c >> 2, kc = c & 3;
            float4 v = *(const float4*)(BT + (size_t)r * K + k0 + kc * 8);
            *(float4*)(Bs + r * 80 + kc * 16) = v;
        }
        __syncthreads();
        bf16x8 af[4], bfr[8];
#pragma unroll
        for (int i = 0; i < 4; ++i)
            af[i] = *(const bf16x8*)(As + (wm + i * 16 + l15) * 80 + g * 16);
#pragma unroll
        for (int j = 0; j < 8; ++j)
            bfr[j] = *(const bf16x8*)(Bs + (wn + j * 16 + l15) * 80 + g * 16);
#pragma unroll
        for (int i = 0; i < 4; ++i)
#pragma unroll
            for (int j = 0; j < 8; ++j)
                acc[i][j] = __builtin_amdgcn_mfma_f32_16x16x32_bf16(af[i], bfr[j], acc[i][j], 0, 0, 0);
        __syncthreads();
    }
    // fp8 store
#pragma unroll
    for (int i = 0; i < 4; ++i)
#pragma unroll
        for (int j = 0; j < 8; ++j) {
            int col = wn + j * 16 + l15;
            int gmb = m0 + wm + i * 16 + g * 4;
            int p01 = __builtin_amdgcn_cvt_pk_fp8_f32(acc[i][j][0], acc[i][j][1], 0, false);
            int p23 = __builtin_amdgcn_cvt_pk_fp8_f32(acc[i][j][2], acc[i][j][3], 0, false);
#pragma unroll
            for (int r = 0; r < 4; ++r) {
                int gm = gmb + r;
                if (gm < M) {
                    int pk = (r < 2) ? p01 : p23;
                    Q[(size_t)gm * 256 + col] = (unsigned char)((pk >> ((r & 1) * 8)) & 0xff);
                }
            }
        }
    // fused dots1: per row, 4 heads per wn-half (head h' covers j=2h',2h'+1)
#pragma unroll
    for (int i = 0; i < 4; ++i)
#pragma unroll
        for (int r = 0; r < 4; ++r) {
            float pes[4], ped[4];
#pragma unroll
            for (int h = 0; h < 4; ++h) {
                int c0 = wn + (2 * h) * 16 + l15;
                int c1 = wn + (2 * h + 1) * 16 + l15;
                pes[h] = acc[i][2 * h][r] * sa[c0] + acc[i][2 * h + 1][r] * sa[c1];
                ped[h] = acc[i][2 * h][r] * sd_[c0] + acc[i][2 * h + 1][r] * sd_[c1];
            }
#pragma unroll
            for (int off = 1; off < 16; off <<= 1) {
#pragma unroll
                for (int h = 0; h < 4; ++h) {
                    pes[h] += __shfl_xor(pes[h], off, 64);
                    ped[h] += __shfl_xor(ped[h], off, 64);
                }
            }
            if (l15 == 0) {
                int gm = m0 + wm + i * 16 + g * 4 + r;
                if (gm < M) {
                    *(float4*)(es1 + (size_t)gm * 8 + 4 * (wid & 1)) = make_float4(pes[0], pes[1], pes[2], pes[3]);
                    *(float4*)(ed1 + (size_t)gm * 8 + 4 * (wid & 1)) = make_float4(ped[0], ped[1], ped[2], ped[3]);
                }
            }
        }
}

// ---------------- gemm2: bf16 C = A @ BT^T, dots2 fused ----------------
__global__ __launch_bounds__(256) void gemm2_k(const unsigned short* __restrict__ A,
                                               const unsigned short* __restrict__ BT,
                                               const float* __restrict__ AS2, const float* __restrict__ AD2,
                                               unsigned short* __restrict__ C,
                                               float* __restrict__ es2, float* __restrict__ ed2, int M) {
    constexpr int N = 64, K = 256, BM = 128, BK = 32, BN = 64;
    __shared__ char As[BM * 80];
    __shared__ char Bs[BN * 80];
    __shared__ float s2a[64], s2d[64];
    __shared__ float red[128][2][2];
    int tid = threadIdx.x;
    if (tid < 64) { s2a[tid] = AS2[tid]; s2d[tid] = AD2[tid]; }
    int m0 = blockIdx.x * BM;
    int wid = tid >> 6, lane = tid & 63;
    int wm = (wid >> 1) * 64, wn = (wid & 1) * 32;
    int l15 = lane & 15, g = lane >> 4;
    f32x4 acc[4][2] = {};

    for (int k0 = 0; k0 < K; k0 += BK) {
#pragma unroll
        for (int i = 0; i < 2; ++i) {
            int c = tid + i * 256;
            int r = c >> 2, kc = c & 3;
            int gm = m0 + r; if (gm >= M) gm = M - 1;
            float4 v = *(const float4*)(A + (size_t)gm * K + k0 + kc * 8);
            *(float4*)(As + r * 80 + kc * 16) = v;
        }
        {
            int c = tid;
            int r = c >> 2, kc = c & 3;
            float4 v = *(const float4*)(BT + (size_t)r * K + k0 + kc * 8);
            *(float4*)(Bs + r * 80 + kc * 16) = v;
        }
        __syncthreads();
        bf16x8 af[4], bfr[2];
#pragma unroll
        for (int i = 0; i < 4; ++i)
            af[i] = *(const bf16x8*)(As + (wm + i * 16 + l15) * 80 + g * 16);
#pragma unroll
        for (int j = 0; j < 2; ++j)
            bfr[j] = *(const bf16x8*)(Bs + (wn + j * 16 + l15) * 80 + g * 16);
#pragma unroll
        for (int i = 0; i < 4; ++i)
#pragma unroll
            for (int j = 0; j < 2; ++j)
                acc[i][j] = __builtin_amdgcn_mfma_f32_16x16x32_bf16(af[i], bfr[j], acc[i][j], 0, 0, 0);
        __syncthreads();
    }
#pragma unroll
    for (int i = 0; i < 4; ++i)
#pragma unroll
        for (int j = 0; j < 2; ++j)
#pragma unroll
            for (int r = 0; r < 4; ++r) {
                int gm = m0 + wm + i * 16 + g * 4 + r;
                if (gm < M)
                    C[(size_t)gm * N + wn + j * 16 + l15] = f2bf(acc[i][j][r]);
            }
    // fused dots2 (single head): half-row partial per wave, combine via LDS
#pragma unroll
    for (int i = 0; i < 4; ++i)
#pragma unroll
        for (int r = 0; r < 4; ++r) {
            int c0 = wn + l15, c1 = wn + 16 + l15;
            float pe = acc[i][0][r] * s2a[c0] + acc[i][1][r] * s2a[c1];
            float pd = acc[i][0][r] * s2d[c0] + acc[i][1][r] * s2d[c1];
#pragma unroll
            for (int off = 1; off < 16; off <<= 1) {
                pe += __shfl_xor(pe, off, 64);
                pd += __shfl_xor(pd, off, 64);
            }
            if (l15 == 0) {
                int rl = wm + i * 16 + g * 4 + r;
                red[rl][wid & 1][0] = pe;
                red[rl][wid & 1][1] = pd;
            }
        }
    __syncthreads();
    if (tid < 128) {
        int gm = m0 + tid;
        if (gm < M) {
            es2[gm] = red[tid][0][0] + red[tid][1][0];
            ed2[gm] = red[tid][0][1] + red[tid][1][1];
        }
    }
}

// ---------------- fused layer-1 aggregation: fp8 gather, 32-bit addressing ----------------
__global__ __launch_bounds__(256) void agg1_k(const unsigned char* __restrict__ xq,
                                              const float* __restrict__ es, const float* __restrict__ ed,
                                              const int* __restrict__ row_ptr, const int* __restrict__ col,
                                              const float* __restrict__ bias, const float* __restrict__ gam,
                                              const float* __restrict__ bet,
                                              unsigned short* __restrict__ hout, int N) {
    int tid = threadIdx.x, wid = tid >> 6, lane = tid & 63;
    int node = blockIdx.x * 4 + wid;
    if (node >= N) return;
    int half = lane >> 5, li = lane & 31;
    unsigned hh = (unsigned)(li >> 2);
    unsigned lib = (unsigned)(li * 8);
    int start = row_ptr[node];
    int deg = row_ptr[node + 1] - start;
    float edh = ed[((unsigned)node << 3) + hh];
    f32x2 acc2[4] = {};
    float wsum = 0.f;

    float esA = 0.f, esB = 0.f, esC = 0.f;
    uint2 xA = {0, 0}, xB = {0, 0}, xC = {0, 0};
    int e = half;
    if (e < deg) { unsigned src = (unsigned)col[start + e];
        esA = es[(src << 3) + hh]; xA = *(const uint2*)(xq + ((src << 8) | lib)); }
    if (e + 2 < deg) { unsigned src = (unsigned)col[start + e + 2];
        esB = es[(src << 3) + hh]; xB = *(const uint2*)(xq + ((src << 8) | lib)); }
    if (e + 4 < deg) { unsigned src = (unsigned)col[start + e + 4];
        esC = es[(src << 3) + hh]; xC = *(const uint2*)(xq + ((src << 8) | lib)); }

#define AGG1_STEP(ESB, XB)                                                        \
    {                                                                             \
        float wgt = __expf(LRELU(ESB + edh));                                     \
        wsum += wgt;                                                              \
        f32x2 w2 = {wgt, wgt};                                                    \
        acc2[0] += w2 * __builtin_amdgcn_cvt_pk_f32_fp8(XB.x, false);             \
        acc2[1] += w2 * __builtin_amdgcn_cvt_pk_f32_fp8(XB.x, true);              \
        acc2[2] += w2 * __builtin_amdgcn_cvt_pk_f32_fp8(XB.y, false);             \
        acc2[3] += w2 * __builtin_amdgcn_cvt_pk_f32_fp8(XB.y, true);              \
        if (e + 6 < deg) {                                                        \
            unsigned src = (unsigned)col[start + e + 6];                          \
            ESB = es[(src << 3) + hh];                                            \
            XB = *(const uint2*)(xq + ((src << 8) | lib));                        \
        }                                                                         \
        e += 2;                                                                   \
    }

    if (e < deg) {
        for (;;) {
            AGG1_STEP(esA, xA);
            if (e >= deg) break;
            AGG1_STEP(esB, xB);
            if (e >= deg) break;
            AGG1_STEP(esC, xC);
            if (e >= deg) break;
        }
    }
#undef AGG1_STEP

    float a8[8];
#pragma unroll
    for (int k = 0; k < 4; ++k) { a8[2 * k] = acc2[k][0]; a8[2 * k + 1] = acc2[k][1]; }
#pragma unroll
    for (int j = 0; j < 8; ++j) a8[j] += __shfl_xor(a8[j], 32, 64);
    wsum += __shfl_xor(wsum, 32, 64);
    float inv = 1.f / wsum;
    float4 bA = *(const float4*)(bias + li * 8);
    float4 bB = *(const float4*)(bias + li * 8 + 4);
    float v[8];
    v[0] = a8[0] * inv + bA.x; v[1] = a8[1] * inv + bA.y;
    v[2] = a8[2] * inv + bA.z; v[3] = a8[3] * inv + bA.w;
    v[4] = a8[4] * inv + bB.x; v[5] = a8[5] * inv + bB.y;
    v[6] = a8[6] * inv + bB.z; v[7] = a8[7] * inv + bB.w;
    float s = 0.f, q = 0.f;
#pragma unroll
    for (int j = 0; j < 8; ++j) { s += v[j]; q += v[j] * v[j]; }
#pragma unroll
    for (int off = 1; off < 32; off <<= 1) { s += __shfl_xor(s, off, 64); q += __shfl_xor(q, off, 64); }
    float mu = s * (1.f / 256.f);
    float var = q * (1.f / 256.f) - mu * mu;
    float rs = rsqrtf(var + 1e-5f);
    float4 gA = *(const float4*)(gam + li * 8);
    float4 gB = *(const float4*)(gam + li * 8 + 4);
    float4 eA = *(const float4*)(bet + li * 8);
    float4 eB = *(const float4*)(bet + li * 8 + 4);
    float o0 = fmaxf((v[0] - mu) * rs * gA.x + eA.x, 0.f);
    float o1 = fmaxf((v[1] - mu) * rs * gA.y + eA.y, 0.f);
    float o2 = fmaxf((v[2] - mu) * rs * gA.z + eA.z, 0.f);
    float o3 = fmaxf((v[3] - mu) * rs * gA.w + eA.w, 0.f);
    float o4 = fmaxf((v[4] - mu) * rs * gB.x + eB.x, 0.f);
    float o5 = fmaxf((v[5] - mu) * rs * gB.y + eB.y, 0.f);
    float o6 = fmaxf((v[6] - mu) * rs * gB.z + eB.z, 0.f);
    float o7 = fmaxf((v[7] - mu) * rs * gB.w + eB.w, 0.f);
    if (half == 0) {
        uint4 pk;
        pk.x = f2bf(o0) | ((unsigned)f2bf(o1) << 16);
        pk.y = f2bf(o2) | ((unsigned)f2bf(o3) << 16);
        pk.z = f2bf(o4) | ((unsigned)f2bf(o5) << 16);
        pk.w = f2bf(o6) | ((unsigned)f2bf(o7) << 16);
        *(uint4*)(hout + (size_t)node * 256 + li * 8) = pk;
    }
}

// ---------------- fused layer-2 aggregation: bf16 gather, 32-bit addressing ----------------
__global__ __launch_bounds__(256) void agg2_k(const unsigned short* __restrict__ xh2,
                                              const float* __restrict__ es, const float* __restrict__ ed,
                                              const int* __restrict__ row_ptr, const int* __restrict__ col,
                                              const float* __restrict__ bias, const float* __restrict__ gam,
                                              const float* __restrict__ bet,
                                              float* __restrict__ out, int N) {
    int tid = threadIdx.x, wid = tid >> 6, lane = tid & 63;
    int node = blockIdx.x * 4 + wid;
    if (node >= N) return;
    int g = lane >> 3, li = lane & 7;
    unsigned lib = (unsigned)(li * 8);
    int start = row_ptr[node];
    int deg = row_ptr[node + 1] - start;
    float edh = ed[node];
    f32x2 acc2[4] = {};
    float wsum = 0.f;

    float esA = 0.f, esB = 0.f, esC = 0.f;
    uint4 xA = {0, 0, 0, 0}, xB = {0, 0, 0, 0}, xC = {0, 0, 0, 0};
    int e = g;
    if (e < deg) { unsigned src = (unsigned)col[start + e];
        esA = es[src]; xA = *(const uint4*)(xh2 + ((src << 6) | lib)); }
    if (e + 8 < deg) { unsigned src = (unsigned)col[start + e + 8];
        esB = es[src]; xB = *(const uint4*)(xh2 + ((src << 6) | lib)); }
    if (e + 16 < deg) { unsigned src = (unsigned)col[start + e + 16];
        esC = es[src]; xC = *(const uint4*)(xh2 + ((src << 6) | lib)); }

#define AGG2_STEP(ESB, XB)                                                        \
    {                                                                             \
        float wgt = __expf(LRELU(ESB + edh));                                     \
        wsum += wgt;                                                              \
        f32x2 w2 = {wgt, wgt};                                                    \
        f32x2 t0 = {__uint_as_float(XB.x << 16), __uint_as_float(XB.x & 0xffff0000u)}; \
        f32x2 t1 = {__uint_as_float(XB.y << 16), __uint_as_float(XB.y & 0xffff0000u)}; \
        f32x2 t2 = {__uint_as_float(XB.z << 16), __uint_as_float(XB.z & 0xffff0000u)}; \
        f32x2 t3 = {__uint_as_float(XB.w << 16), __uint_as_float(XB.w & 0xffff0000u)}; \
        acc2[0] += w2 * t0;                                                       \
        acc2[1] += w2 * t1;                                                       \
        acc2[2] += w2 * t2;                                                       \
        acc2[3] += w2 * t3;                                                       \
        if (e + 24 < deg) {                                                       \
            unsigned src = (unsigned)col[start + e + 24];                         \
            ESB = es[src];                                                        \
            XB = *(const uint4*)(xh2 + ((src << 6) | lib));                       \
        }                                                                         \
        e += 8;                                                                   \
    }

    if (e < deg) {
        for (;;) {
            AGG2_STEP(esA, xA);
            if (e >= deg) break;
            AGG2_STEP(esB, xB);
            if (e >= deg) break;
            AGG2_STEP(esC, xC);
            if (e >= deg) break;
        }
    }
#undef AGG2_STEP

    float a8[8];
#pragma unroll
    for (int k = 0; k < 4; ++k) { a8[2 * k] = acc2[k][0]; a8[2 * k + 1] = acc2[k][1]; }
#pragma unroll
    for (int off = 8; off < 64; off <<= 1) {
#pragma unroll
        for (int j = 0; j < 8; ++j) a8[j] += __shfl_xor(a8[j], off, 64);
        wsum += __shfl_xor(wsum, off, 64);
    }
    int c = li * 8;
    float inv = 1.f / wsum;
    float v[8];
#pragma unroll
    for (int j = 0; j < 8; ++j) v[j] = a8[j] * inv + bias[c + j];
    float s = 0.f, q = 0.f;
#pragma unroll
    for (int j = 0; j < 8; ++j) { s += v[j]; q += v[j] * v[j]; }
#pragma unroll
    for (int off = 1; off < 8; off <<= 1) { s += __shfl_xor(s, off, 64); q += __shfl_xor(q, off, 64); }
    float mu = s * (1.f / 64.f);
    float var = q * (1.f / 64.f) - mu * mu;
    float rs = rsqrtf(var + 1e-5f);
    float o[8];
    float mx = -1e30f;
#pragma unroll
    for (int j = 0; j < 8; ++j) {
        o[j] = (v[j] - mu) * rs * gam[c + j] + bet[c + j];
        mx = fmaxf(mx, o[j]);
    }
#pragma unroll
    for (int off = 1; off < 8; off <<= 1) mx = fmaxf(mx, __shfl_xor(mx, off, 64));
    float se = 0.f;
#pragma unroll
    for (int j = 0; j < 8; ++j) se += __expf(o[j] - mx);
#pragma unroll
    for (int off = 1; off < 8; off <<= 1) se += __shfl_xor(se, off, 64);
    float lse = mx + logf(se);
    if (g == 0) {
        float4 o0 = make_float4(o[0] - lse, o[1] - lse, o[2] - lse, o[3] - lse);
        float4 o1 = make_float4(o[4] - lse, o[5] - lse, o[6] - lse, o[7] - lse);
        *(float4*)(out + (size_t)node * 64 + c) = o0;
        *(float4*)(out + (size_t)node * 64 + c + 4) = o1;
    }
}

extern "C" void kernel_launch(void* const* d_in, const int* in_sizes, int n_in,
                              void* d_out, int out_size, void* d_ws, size_t ws_size,
                              hipStream_t stream) {
    const float* x   = (const float*)d_in[0];
    const int*   edge = (const int*)d_in[1];
    const float* W1  = (const float*)d_in[2];
    const float* as1 = (const float*)d_in[3];
    const float* ad1 = (const float*)d_in[4];
    const float* b1  = (const float*)d_in[5];
    const float* g1  = (const float*)d_in[6];
    const float* be1 = (const float*)d_in[7];
    const float* W2  = (const float*)d_in[8];
    const float* as2 = (const float*)d_in[9];
    const float* ad2 = (const float*)d_in[10];
    const float* b2  = (const float*)d_in[11];
    const float* g2  = (const float*)d_in[12];
    const float* be2 = (const float*)d_in[13];

    int NN = in_sizes[0] / 256;
    int E  = in_sizes[1] / 2;
    int ET = E + NN;

    char* w = (char*)d_ws;
    size_t off = 0;
    auto nxt = [&](size_t b) -> void* {
        void* p = w + off;
        off = (off + b + 255) & ~(size_t)255;
        return p;
    };
    unsigned short* W1T  = (unsigned short*)nxt(256 * 256 * 2);
    unsigned short* W2T  = (unsigned short*)nxt(64 * 256 * 2);
    unsigned char*  xq   = (unsigned char*)nxt((size_t)NN * 256);
    unsigned short* hbuf = (unsigned short*)nxt((size_t)NN * 256 * 2);
    unsigned short* xh2b = (unsigned short*)nxt((size_t)NN * 64 * 2);
    float* es1   = (float*)nxt((size_t)NN * 8 * 4);
    float* ed1   = (float*)nxt((size_t)NN * 8 * 4);
    float* es2   = (float*)nxt((size_t)NN * 4);
    float* ed2   = (float*)nxt((size_t)NN * 4);
    int* row_ptr = (int*)nxt((size_t)(NN + 1) * 4);
    int* tmpN    = (int*)nxt((size_t)NN * 4);
    int* rank    = (int*)nxt((size_t)E * 4);
    int* col     = (int*)nxt((size_t)ET * 4);
    int* bsum    = (int*)nxt(1024 * 4);
    (void)ws_size; (void)n_in; (void)out_size;

    int NB = (NN + 1023) / 1024;

    // CSR build
    (void)hipMemsetAsync(tmpN, 0, (size_t)NN * 4, stream);
    prep_k<<<320 + (E + 255) / 256, 256, 0, stream>>>(W1, W1T, W2, W2T, edge, tmpN, rank, E);
    psum_k<<<NB, 256, 0, stream>>>(tmpN, bsum, NN);
    bscan_k<<<1, 128, 0, stream>>>(bsum, NB);
    rowptr_k<<<NB, 256, 0, stream>>>(tmpN, bsum, row_ptr, NN);
    scatter_k<<<(ET + 255) / 256, 256, 0, stream>>>(edge, row_ptr, rank, col, E, NN);

    // Layer 1 (dots1 fused into gemm1f)
    gemm1f_k<<<(NN + 127) / 128, 256, 0, stream>>>(x, W1T, as1, ad1, xq, es1, ed1, NN);
    agg1_k<<<(NN + 3) / 4, 256, 0, stream>>>(xq, es1, ed1, row_ptr, col, b1, g1, be1, hbuf, NN);

    // Layer 2 (dots2 fused into gemm2)
    gemm2_k<<<(NN + 127) / 128, 256, 0, stream>>>(hbuf, W2T, as2, ad2, xh2b, es2, ed2, NN);
    agg2_k<<<(NN + 3) / 4, 256, 0, stream>>>(xh2b, es2, ed2, row_ptr, col, b2, g2, be2,
                                             (float*)d_out, NN);
}

// Round 13
// 373.431 us; speedup vs baseline: 1.0076x; 1.0076x over previous
//
#include <hip/hip_runtime.h>
#include <math.h>

#define LRELU(v) ((v) > 0.0f ? (v) : 0.2f * (v))

typedef __bf16 bf16x8 __attribute__((ext_vector_type(8)));
typedef float f32x4 __attribute__((ext_vector_type(4)));
typedef float f32x2 __attribute__((ext_vector_type(2)));

__device__ __forceinline__ unsigned short f2bf(float f) {
    unsigned int u = __float_as_uint(f);
    u += 0x7FFF + ((u >> 16) & 1);
    return (unsigned short)(u >> 16);
}
__device__ __forceinline__ float bf2f(unsigned short s) {
    return __uint_as_float(((unsigned int)s) << 16);
}

// ---------------- prep: W1T cast + W2T cast + hist/rank ----------------
__global__ __launch_bounds__(256) void prep_k(const float* __restrict__ W1, unsigned short* __restrict__ W1T,
                                              const float* __restrict__ W2, unsigned short* __restrict__ W2T,
                                              const int* __restrict__ edge, int* __restrict__ cnt,
                                              int* __restrict__ rank, int E) {
    int b = blockIdx.x;
    if (b < 256) {
        int i = b * 256 + threadIdx.x;
        int k = i >> 8, n = i & 255;
        W1T[(size_t)n * 256 + k] = f2bf(W1[i]);
    } else if (b < 320) {
        int i = (b - 256) * 256 + threadIdx.x;
        int k = i >> 6, n = i & 63;
        W2T[(size_t)n * 256 + k] = f2bf(W2[i]);
    } else {
        int i = (b - 320) * 256 + threadIdx.x;
        if (i < E) rank[i] = atomicAdd(&cnt[edge[E + i]], 1);
    }
}

// ---------------- scan hierarchy ----------------
__global__ __launch_bounds__(256) void psum_k(const int* __restrict__ cnt, int* __restrict__ bsum, int N) {
    __shared__ int wsh[4];
    int b = blockIdx.x;
    int gi = b * 1024 + threadIdx.x * 4;
    int s = 0;
    if (gi + 3 < N) {
        int4 v = *(const int4*)(cnt + gi);
        s = v.x + v.y + v.z + v.w + 4;
    } else {
        for (int j = 0; j < 4; ++j) if (gi + j < N) s += cnt[gi + j] + 1;
    }
#pragma unroll
    for (int off = 1; off < 64; off <<= 1) s += __shfl_xor(s, off, 64);
    if ((threadIdx.x & 63) == 0) wsh[threadIdx.x >> 6] = s;
    __syncthreads();
    if (threadIdx.x == 0) bsum[b] = wsh[0] + wsh[1] + wsh[2] + wsh[3];
}

__global__ void bscan_k(int* __restrict__ bsum, int B) {
    __shared__ int sh[128];
    int t = threadIdx.x;
    int v = (t < B) ? bsum[t] : 0;
    sh[t] = v;
    __syncthreads();
    for (int off = 1; off < 128; off <<= 1) {
        int u = (t >= off) ? sh[t - off] : 0;
        __syncthreads();
        sh[t] += u;
        __syncthreads();
    }
    if (t < B) bsum[t] = sh[t] - v;  // exclusive prefix
}

__global__ __launch_bounds__(256) void rowptr_k(const int* __restrict__ cnt, const int* __restrict__ bsum,
                                                int* __restrict__ row_ptr, int N) {
    __shared__ int wsh[4];
    int b = blockIdx.x;
    int t = threadIdx.x;
    int gi = b * 1024 + t * 4;
    int c[4];
    int s = 0;
#pragma unroll
    for (int j = 0; j < 4; ++j) {
        int i = gi + j;
        c[j] = (i < N) ? cnt[i] + 1 : 0;
        s += c[j];
    }
    int lane = t & 63, w = t >> 6;
    int ps = s;
#pragma unroll
    for (int off = 1; off < 64; off <<= 1) {
        int u = __shfl_up(ps, off, 64);
        if (lane >= off) ps += u;
    }
    if (lane == 63) wsh[w] = ps;
    __syncthreads();
    int wbase = 0;
    for (int k = 0; k < w; ++k) wbase += wsh[k];
    int base = bsum[b] + wbase + (ps - s);
#pragma unroll
    for (int j = 0; j < 4; ++j) {
        int i = gi + j;
        if (i < N) row_ptr[i] = base;
        base += c[j];
    }
    if (N - 1 >= gi && N - 1 < gi + 4) row_ptr[N] = base;
}

// ---------------- counting-sort placement (no atomics) ----------------
__global__ void scatter_k(const int* __restrict__ edge, const int* __restrict__ row_ptr,
                          const int* __restrict__ rank, int* __restrict__ col, int E, int N) {
    int i = blockIdx.x * blockDim.x + threadIdx.x;
    if (i < E) {
        int dst = edge[E + i];
        col[row_ptr[dst] + rank[i]] = edge[i];
    } else if (i < E + N) {
        int n = i - E;
        col[row_ptr[n + 1] - 1] = n;    // self-loop in last slot
    }
}

// ---------------- gemm1: fp8 Q = f32 A @ BT^T (cast fused, no bf16 out) ----------------
__global__ __launch_bounds__(256) void gemm1f_k(const float* __restrict__ A,
                                                const unsigned short* __restrict__ BT,
                                                unsigned char* __restrict__ Q, int M) {
    constexpr int K = 256, BM = 128, BK = 32;
    __shared__ char As[BM * 80];
    __shared__ char Bs[256 * 80];
    int tid = threadIdx.x;
    int m0 = blockIdx.x * BM;
    int wid = tid >> 6, lane = tid & 63;
    int wm = (wid >> 1) * 64, wn = (wid & 1) * 128;
    int l15 = lane & 15, g = lane >> 4;
    f32x4 acc[4][8] = {};

    for (int k0 = 0; k0 < K; k0 += BK) {
#pragma unroll
        for (int i = 0; i < 2; ++i) {
            int c = tid + i * 256;
            int r = c >> 2, kc = c & 3;
            int gm = m0 + r; if (gm >= M) gm = M - 1;
            const float* src = A + (size_t)gm * K + k0 + kc * 8;
            float4 v0 = *(const float4*)(src);
            float4 v1 = *(const float4*)(src + 4);
            uint4 pk;
            pk.x = f2bf(v0.x) | ((unsigned)f2bf(v0.y) << 16);
            pk.y = f2bf(v0.z) | ((unsigned)f2bf(v0.w) << 16);
            pk.z = f2bf(v1.x) | ((unsigned)f2bf(v1.y) << 16);
            pk.w = f2bf(v1.z) | ((unsigned)f2bf(v1.w) << 16);
            *(uint4*)(As + r * 80 + kc * 16) = pk;
        }
#pragma unroll
        for (int i = 0; i < 4; ++i) {
            int c = tid + i * 256;
            int r = c >> 2, kc = c & 3;
            float4 v = *(const float4*)(BT + (size_t)r * K + k0 + kc * 8);
            *(float4*)(Bs + r * 80 + kc * 16) = v;
        }
        __syncthreads();
        bf16x8 af[4], bfr[8];
#pragma unroll
        for (int i = 0; i < 4; ++i)
            af[i] = *(const bf16x8*)(As + (wm + i * 16 + l15) * 80 + g * 16);
#pragma unroll
        for (int j = 0; j < 8; ++j)
            bfr[j] = *(const bf16x8*)(Bs + (wn + j * 16 + l15) * 80 + g * 16);
#pragma unroll
        for (int i = 0; i < 4; ++i)
#pragma unroll
            for (int j = 0; j < 8; ++j)
                acc[i][j] = __builtin_amdgcn_mfma_f32_16x16x32_bf16(af[i], bfr[j], acc[i][j], 0, 0, 0);
        __syncthreads();
    }
#pragma unroll
    for (int i = 0; i < 4; ++i)
#pragma unroll
        for (int j = 0; j < 8; ++j) {
            int col = wn + j * 16 + l15;
            int gmb = m0 + wm + i * 16 + g * 4;
            int p01 = __builtin_amdgcn_cvt_pk_fp8_f32(acc[i][j][0], acc[i][j][1], 0, false);
            int p23 = __builtin_amdgcn_cvt_pk_fp8_f32(acc[i][j][2], acc[i][j][3], 0, false);
#pragma unroll
            for (int r = 0; r < 4; ++r) {
                int gm = gmb + r;
                if (gm < M) {
                    int pk = (r < 2) ? p01 : p23;
                    Q[(size_t)gm * 256 + col] = (unsigned char)((pk >> ((r & 1) * 8)) & 0xff);
                }
            }
        }
}

// ---------------- gemm2: bf16 A @ BT, BN=64 ----------------
__global__ __launch_bounds__(256) void gemm2_k(const unsigned short* __restrict__ A,
                                               const unsigned short* __restrict__ BT,
                                               unsigned short* __restrict__ C,
                                               int M, int N, int K) {
    constexpr int BM = 128, BK = 32, BN = 64;
    __shared__ char As[BM * 80];
    __shared__ char Bs[BN * 80];
    int tid = threadIdx.x;
    int m0 = blockIdx.x * BM;
    int wid = tid >> 6, lane = tid & 63;
    int wm = (wid >> 1) * 64, wn = (wid & 1) * 32;
    int l15 = lane & 15, g = lane >> 4;
    f32x4 acc[4][2] = {};

    for (int k0 = 0; k0 < K; k0 += BK) {
#pragma unroll
        for (int i = 0; i < 2; ++i) {
            int c = tid + i * 256;
            int r = c >> 2, kc = c & 3;
            int gm = m0 + r; if (gm >= M) gm = M - 1;
            float4 v = *(const float4*)(A + (size_t)gm * K + k0 + kc * 8);
            *(float4*)(As + r * 80 + kc * 16) = v;
        }
        {
            int c = tid;
            int r = c >> 2, kc = c & 3;
            float4 v = *(const float4*)(BT + (size_t)r * K + k0 + kc * 8);
            *(float4*)(Bs + r * 80 + kc * 16) = v;
        }
        __syncthreads();
        bf16x8 af[4], bfr[2];
#pragma unroll
        for (int i = 0; i < 4; ++i)
            af[i] = *(const bf16x8*)(As + (wm + i * 16 + l15) * 80 + g * 16);
#pragma unroll
        for (int j = 0; j < 2; ++j)
            bfr[j] = *(const bf16x8*)(Bs + (wn + j * 16 + l15) * 80 + g * 16);
#pragma unroll
        for (int i = 0; i < 4; ++i)
#pragma unroll
            for (int j = 0; j < 2; ++j)
                acc[i][j] = __builtin_amdgcn_mfma_f32_16x16x32_bf16(af[i], bfr[j], acc[i][j], 0, 0, 0);
        __syncthreads();
    }
#pragma unroll
    for (int i = 0; i < 4; ++i)
#pragma unroll
        for (int j = 0; j < 2; ++j)
#pragma unroll
            for (int r = 0; r < 4; ++r) {
                int gm = m0 + wm + i * 16 + g * 4 + r;
                if (gm < M)
                    C[(size_t)gm * N + wn + j * 16 + l15] = f2bf(acc[i][j][r]);
            }
}

// ---------------- attention logits: dots1 reads fp8 ----------------
__global__ void dots1_k(const unsigned char* __restrict__ xq, const float* __restrict__ as_,
                        const float* __restrict__ ad_, float* __restrict__ es,
                        float* __restrict__ ed, int N8) {
    __shared__ float ws[256], wd[256];
    ws[threadIdx.x] = as_[threadIdx.x];
    wd[threadIdx.x] = ad_[threadIdx.x];
    __syncthreads();
    int idx = blockIdx.x * 256 + threadIdx.x;
    if (idx >= N8) return;
    int n = idx >> 3, hh = idx & 7;
    const uint4* p = (const uint4*)(xq + (size_t)n * 256 + hh * 32);
    const float* s = ws + hh * 32;
    const float* d = wd + hh * 32;
    float a = 0.f, b = 0.f;
#pragma unroll
    for (int j = 0; j < 2; ++j) {
        uint4 v = p[j];
        unsigned dws[4] = {v.x, v.y, v.z, v.w};
#pragma unroll
        for (int k = 0; k < 4; ++k) {
            int c0 = j * 16 + k * 4;
            f32x2 lo = __builtin_amdgcn_cvt_pk_f32_fp8(dws[k], false);
            f32x2 hi = __builtin_amdgcn_cvt_pk_f32_fp8(dws[k], true);
            a += lo[0] * s[c0] + lo[1] * s[c0 + 1] + hi[0] * s[c0 + 2] + hi[1] * s[c0 + 3];
            b += lo[0] * d[c0] + lo[1] * d[c0 + 1] + hi[0] * d[c0 + 2] + hi[1] * d[c0 + 3];
        }
    }
    es[idx] = a;
    ed[idx] = b;
}

__global__ void dots2_k(const unsigned short* __restrict__ xh2, const float* __restrict__ as_,
                        const float* __restrict__ ad_, float* __restrict__ es,
                        float* __restrict__ ed, int N) {
    __shared__ float ws[64], wd[64];
    if (threadIdx.x < 64) { ws[threadIdx.x] = as_[threadIdx.x]; wd[threadIdx.x] = ad_[threadIdx.x]; }
    __syncthreads();
    int n = blockIdx.x * blockDim.x + threadIdx.x;
    if (n >= N) return;
    const ushort4* p = (const ushort4*)(xh2 + (size_t)n * 64);
    float a = 0.f, b = 0.f;
#pragma unroll
    for (int j = 0; j < 16; ++j) {
        ushort4 v = p[j];
        a += bf2f(v.x) * ws[j * 4 + 0] + bf2f(v.y) * ws[j * 4 + 1] +
             bf2f(v.z) * ws[j * 4 + 2] + bf2f(v.w) * ws[j * 4 + 3];
        b += bf2f(v.x) * wd[j * 4 + 0] + bf2f(v.y) * wd[j * 4 + 1] +
             bf2f(v.z) * wd[j * 4 + 2] + bf2f(v.w) * wd[j * 4 + 3];
    }
    es[n] = a;
    ed[n] = b;
}

// ---------------- fused layer-1 aggregation: fp8 gather, 2 streams x 2-deep per half-wave ----------------
__global__ __launch_bounds__(256) void agg1_k(const unsigned char* __restrict__ xq,
                                              const float* __restrict__ es, const float* __restrict__ ed,
                                              const int* __restrict__ row_ptr, const int* __restrict__ col,
                                              const float* __restrict__ bias, const float* __restrict__ gam,
                                              const float* __restrict__ bet,
                                              unsigned short* __restrict__ hout, int N) {
    int tid = threadIdx.x, wid = tid >> 6, lane = tid & 63;
    int node = blockIdx.x * 4 + wid;
    if (node >= N) return;
    int half = lane >> 5, li = lane & 31;
    unsigned hh = (unsigned)(li >> 2);
    unsigned lib = (unsigned)(li * 8);
    int start = row_ptr[node];
    int deg = row_ptr[node + 1] - start;
    float edh = ed[((unsigned)node << 3) + hh];
    f32x2 acc2[4] = {};
    float wsum = 0.f;

    // two interleaved streams per half-wave (even/odd), each double-buffered:
    // stream A covers edges {2*half + 4k}, stream B {2*half+1 + 4k}
    int eA = half * 2, eB = half * 2 + 1;
    float esA0 = 0.f, esA1 = 0.f, esB0 = 0.f, esB1 = 0.f;
    uint2 xA0 = {0, 0}, xA1 = {0, 0}, xB0 = {0, 0}, xB1 = {0, 0};

#define LD1(E, ES, XB) { unsigned src = (unsigned)col[start + (E)];               \
        ES = es[(src << 3) + hh]; XB = *(const uint2*)(xq + ((src << 8) | lib)); }
#define CONS1(ES, XB) { float wgt = __expf(LRELU(ES + edh)); wsum += wgt;         \
        f32x2 w2 = {wgt, wgt};                                                    \
        acc2[0] += w2 * __builtin_amdgcn_cvt_pk_f32_fp8(XB.x, false);             \
        acc2[1] += w2 * __builtin_amdgcn_cvt_pk_f32_fp8(XB.x, true);              \
        acc2[2] += w2 * __builtin_amdgcn_cvt_pk_f32_fp8(XB.y, false);             \
        acc2[3] += w2 * __builtin_amdgcn_cvt_pk_f32_fp8(XB.y, true); }

    if (eA < deg) LD1(eA, esA0, xA0);
    if (eB < deg) LD1(eB, esB0, xB0);
    if (eA + 4 < deg) LD1(eA + 4, esA1, xA1);
    if (eB + 4 < deg) LD1(eB + 4, esB1, xB1);

    while (eA < deg || eB < deg) {
        if (eA < deg) { CONS1(esA0, xA0); if (eA + 8 < deg) LD1(eA + 8, esA0, xA0); }
        if (eB < deg) { CONS1(esB0, xB0); if (eB + 8 < deg) LD1(eB + 8, esB0, xB0); }
        eA += 4; eB += 4;
        if (eA < deg) { CONS1(esA1, xA1); if (eA + 8 < deg) LD1(eA + 8, esA1, xA1); }
        if (eB < deg) { CONS1(esB1, xB1); if (eB + 8 < deg) LD1(eB + 8, esB1, xB1); }
        eA += 4; eB += 4;
    }
#undef LD1
#undef CONS1

    float a8[8];
#pragma unroll
    for (int k = 0; k < 4; ++k) { a8[2 * k] = acc2[k][0]; a8[2 * k + 1] = acc2[k][1]; }
#pragma unroll
    for (int j = 0; j < 8; ++j) a8[j] += __shfl_xor(a8[j], 32, 64);
    wsum += __shfl_xor(wsum, 32, 64);
    float inv = 1.f / wsum;
    float4 bA = *(const float4*)(bias + li * 8);
    float4 bB = *(const float4*)(bias + li * 8 + 4);
    float v[8];
    v[0] = a8[0] * inv + bA.x; v[1] = a8[1] * inv + bA.y;
    v[2] = a8[2] * inv + bA.z; v[3] = a8[3] * inv + bA.w;
    v[4] = a8[4] * inv + bB.x; v[5] = a8[5] * inv + bB.y;
    v[6] = a8[6] * inv + bB.z; v[7] = a8[7] * inv + bB.w;
    float s = 0.f, q = 0.f;
#pragma unroll
    for (int j = 0; j < 8; ++j) { s += v[j]; q += v[j] * v[j]; }
#pragma unroll
    for (int off = 1; off < 32; off <<= 1) { s += __shfl_xor(s, off, 64); q += __shfl_xor(q, off, 64); }
    float mu = s * (1.f / 256.f);
    float var = q * (1.f / 256.f) - mu * mu;
    float rs = rsqrtf(var + 1e-5f);
    float4 gA = *(const float4*)(gam + li * 8);
    float4 gB = *(const float4*)(gam + li * 8 + 4);
    float4 eA4 = *(const float4*)(bet + li * 8);
    float4 eB4 = *(const float4*)(bet + li * 8 + 4);
    float o0 = fmaxf((v[0] - mu) * rs * gA.x + eA4.x, 0.f);
    float o1 = fmaxf((v[1] - mu) * rs * gA.y + eA4.y, 0.f);
    float o2 = fmaxf((v[2] - mu) * rs * gA.z + eA4.z, 0.f);
    float o3 = fmaxf((v[3] - mu) * rs * gA.w + eA4.w, 0.f);
    float o4 = fmaxf((v[4] - mu) * rs * gB.x + eB4.x, 0.f);
    float o5 = fmaxf((v[5] - mu) * rs * gB.y + eB4.y, 0.f);
    float o6 = fmaxf((v[6] - mu) * rs * gB.z + eB4.z, 0.f);
    float o7 = fmaxf((v[7] - mu) * rs * gB.w + eB4.w, 0.f);
    if (half == 0) {
        uint4 pk;
        pk.x = f2bf(o0) | ((unsigned)f2bf(o1) << 16);
        pk.y = f2bf(o2) | ((unsigned)f2bf(o3) << 16);
        pk.z = f2bf(o4) | ((unsigned)f2bf(o5) << 16);
        pk.w = f2bf(o6) | ((unsigned)f2bf(o7) << 16);
        *(uint4*)(hout + (size_t)node * 256 + li * 8) = pk;
    }
}

// ---------------- fused layer-2 aggregation: bf16 gather, 32-bit addressing ----------------
__global__ __launch_bounds__(256) void agg2_k(const unsigned short* __restrict__ xh2,
                                              const float* __restrict__ es, const float* __restrict__ ed,
                                              const int* __restrict__ row_ptr, const int* __restrict__ col,
                                              const float* __restrict__ bias, const float* __restrict__ gam,
                                              const float* __restrict__ bet,
                                              float* __restrict__ out, int N) {
    int tid = threadIdx.x, wid = tid >> 6, lane = tid & 63;
    int node = blockIdx.x * 4 + wid;
    if (node >= N) return;
    int g = lane >> 3, li = lane & 7;
    unsigned lib = (unsigned)(li * 8);
    int start = row_ptr[node];
    int deg = row_ptr[node + 1] - start;
    float edh = ed[node];
    f32x2 acc2[4] = {};
    float wsum = 0.f;

    float esA = 0.f, esB = 0.f, esC = 0.f;
    uint4 xA = {0, 0, 0, 0}, xB = {0, 0, 0, 0}, xC = {0, 0, 0, 0};
    int e = g;
    if (e < deg) { unsigned src = (unsigned)col[start + e];
        esA = es[src]; xA = *(const uint4*)(xh2 + ((src << 6) | lib)); }
    if (e + 8 < deg) { unsigned src = (unsigned)col[start + e + 8];
        esB = es[src]; xB = *(const uint4*)(xh2 + ((src << 6) | lib)); }
    if (e + 16 < deg) { unsigned src = (unsigned)col[start + e + 16];
        esC = es[src]; xC = *(const uint4*)(xh2 + ((src << 6) | lib)); }

#define AGG2_STEP(ESB, XB)                                                        \
    {                                                                             \
        float wgt = __expf(LRELU(ESB + edh));                                     \
        wsum += wgt;                                                              \
        f32x2 w2 = {wgt, wgt};                                                    \
        f32x2 t0 = {__uint_as_float(XB.x << 16), __uint_as_float(XB.x & 0xffff0000u)}; \
        f32x2 t1 = {__uint_as_float(XB.y << 16), __uint_as_float(XB.y & 0xffff0000u)}; \
        f32x2 t2 = {__uint_as_float(XB.z << 16), __uint_as_float(XB.z & 0xffff0000u)}; \
        f32x2 t3 = {__uint_as_float(XB.w << 16), __uint_as_float(XB.w & 0xffff0000u)}; \
        acc2[0] += w2 * t0;                                                       \
        acc2[1] += w2 * t1;                                                       \
        acc2[2] += w2 * t2;                                                       \
        acc2[3] += w2 * t3;                                                       \
        if (e + 24 < deg) {                                                       \
            unsigned src = (unsigned)col[start + e + 24];                         \
            ESB = es[src];                                                        \
            XB = *(const uint4*)(xh2 + ((src << 6) | lib));                       \
        }                                                                         \
        e += 8;                                                                   \
    }

    if (e < deg) {
        for (;;) {
            AGG2_STEP(esA, xA);
            if (e >= deg) break;
            AGG2_STEP(esB, xB);
            if (e >= deg) break;
            AGG2_STEP(esC, xC);
            if (e >= deg) break;
        }
    }
#undef AGG2_STEP

    float a8[8];
#pragma unroll
    for (int k = 0; k < 4; ++k) { a8[2 * k] = acc2[k][0]; a8[2 * k + 1] = acc2[k][1]; }
#pragma unroll
    for (int off = 8; off < 64; off <<= 1) {
#pragma unroll
        for (int j = 0; j < 8; ++j) a8[j] += __shfl_xor(a8[j], off, 64);
        wsum += __shfl_xor(wsum, off, 64);
    }
    int c = li * 8;
    float inv = 1.f / wsum;
    float v[8];
#pragma unroll
    for (int j = 0; j < 8; ++j) v[j] = a8[j] * inv + bias[c + j];
    float s = 0.f, q = 0.f;
#pragma unroll
    for (int j = 0; j < 8; ++j) { s += v[j]; q += v[j] * v[j]; }
#pragma unroll
    for (int off = 1; off < 8; off <<= 1) { s += __shfl_xor(s, off, 64); q += __shfl_xor(q, off, 64); }
    float mu = s * (1.f / 64.f);
    float var = q * (1.f / 64.f) - mu * mu;
    float rs = rsqrtf(var + 1e-5f);
    float o[8];
    float mx = -1e30f;
#pragma unroll
    for (int j = 0; j < 8; ++j) {
        o[j] = (v[j] - mu) * rs * gam[c + j] + bet[c + j];
        mx = fmaxf(mx, o[j]);
    }
#pragma unroll
    for (int off = 1; off < 8; off <<= 1) mx = fmaxf(mx, __shfl_xor(mx, off, 64));
    float se = 0.f;
#pragma unroll
    for (int j = 0; j < 8; ++j) se += __expf(o[j] - mx);
#pragma unroll
    for (int off = 1; off < 8; off <<= 1) se += __shfl_xor(se, off, 64);
    float lse = mx + logf(se);
    if (g == 0) {
        float4 o0 = make_float4(o[0] - lse, o[1] - lse, o[2] - lse, o[3] - lse);
        float4 o1 = make_float4(o[4] - lse, o[5] - lse, o[6] - lse, o[7] - lse);
        *(float4*)(out + (size_t)node * 64 + c) = o0;
        *(float4*)(out + (size_t)node * 64 + c + 4) = o1;
    }
}

extern "C" void kernel_launch(void* const* d_in, const int* in_sizes, int n_in,
                              void* d_out, int out_size, void* d_ws, size_t ws_size,
                              hipStream_t stream) {
    const float* x   = (const float*)d_in[0];
    const int*   edge = (const int*)d_in[1];
    const float* W1  = (const float*)d_in[2];
    const float* as1 = (const float*)d_in[3];
    const float* ad1 = (const float*)d_in[4];
    const float* b1  = (const float*)d_in[5];
    const float* g1  = (const float*)d_in[6];
    const float* be1 = (const float*)d_in[7];
    const float* W2  = (const float*)d_in[8];
    const float* as2 = (const float*)d_in[9];
    const float* ad2 = (const float*)d_in[10];
    const float* b2  = (const float*)d_in[11];
    const float* g2  = (const float*)d_in[12];
    const float* be2 = (const float*)d_in[13];

    int NN = in_sizes[0] / 256;
    int E  = in_sizes[1] / 2;
    int ET = E + NN;

    char* w = (char*)d_ws;
    size_t off = 0;
    auto nxt = [&](size_t b) -> void* {
        void* p = w + off;
        off = (off + b + 255) & ~(size_t)255;
        return p;
    };
    unsigned short* W1T  = (unsigned short*)nxt(256 * 256 * 2);
    unsigned short* W2T  = (unsigned short*)nxt(64 * 256 * 2);
    unsigned char*  xq   = (unsigned char*)nxt((size_t)NN * 256);
    unsigned short* hbuf = (unsigned short*)nxt((size_t)NN * 256 * 2);
    unsigned short* xh2b = (unsigned short*)nxt((size_t)NN * 64 * 2);
    float* es1   = (float*)nxt((size_t)NN * 8 * 4);
    float* ed1   = (float*)nxt((size_t)NN * 8 * 4);
    float* es2   = (float*)nxt((size_t)NN * 4);
    float* ed2   = (float*)nxt((size_t)NN * 4);
    int* row_ptr = (int*)nxt((size_t)(NN + 1) * 4);
    int* tmpN    = (int*)nxt((size_t)NN * 4);
    int* rank    = (int*)nxt((size_t)E * 4);
    int* col     = (int*)nxt((size_t)ET * 4);
    int* bsum    = (int*)nxt(1024 * 4);
    (void)ws_size; (void)n_in; (void)out_size;

    int NB = (NN + 1023) / 1024;

    // CSR build
    (void)hipMemsetAsync(tmpN, 0, (size_t)NN * 4, stream);
    prep_k<<<320 + (E + 255) / 256, 256, 0, stream>>>(W1, W1T, W2, W2T, edge, tmpN, rank, E);
    psum_k<<<NB, 256, 0, stream>>>(tmpN, bsum, NN);
    bscan_k<<<1, 128, 0, stream>>>(bsum, NB);
    rowptr_k<<<NB, 256, 0, stream>>>(tmpN, bsum, row_ptr, NN);
    scatter_k<<<(ET + 255) / 256, 256, 0, stream>>>(edge, row_ptr, rank, col, E, NN);

    // Layer 1
    gemm1f_k<<<(NN + 127) / 128, 256, 0, stream>>>(x, W1T, xq, NN);
    dots1_k<<<(NN * 8 + 255) / 256, 256, 0, stream>>>(xq, as1, ad1, es1, ed1, NN * 8);
    agg1_k<<<(NN + 3) / 4, 256, 0, stream>>>(xq, es1, ed1, row_ptr, col, b1, g1, be1, hbuf, NN);

    // Layer 2
    gemm2_k<<<(NN + 127) / 128, 256, 0, stream>>>(hbuf, W2T, xh2b, NN, 64, 256);
    dots2_k<<<(NN + 255) / 256, 256, 0, stream>>>(xh2b, as2, ad2, es2, ed2, NN);
    agg2_k<<<(NN + 3) / 4, 256, 0, stream>>>(xh2b, es2, ed2, row_ptr, col, b2, g2, be2,
                                             (float*)d_out, NN);
}

// Round 14
// 350.167 us; speedup vs baseline: 1.0746x; 1.0664x over previous
//
#include <hip/hip_runtime.h>
#include <math.h>

#define LRELU(v) ((v) > 0.0f ? (v) : 0.2f * (v))

typedef __bf16 bf16x8 __attribute__((ext_vector_type(8)));
typedef float f32x4 __attribute__((ext_vector_type(4)));
typedef float f32x2 __attribute__((ext_vector_type(2)));

__device__ __forceinline__ unsigned short f2bf(float f) {
    unsigned int u = __float_as_uint(f);
    u += 0x7FFF + ((u >> 16) & 1);
    return (unsigned short)(u >> 16);
}
__device__ __forceinline__ float bf2f(unsigned short s) {
    return __uint_as_float(((unsigned int)s) << 16);
}

// ---------------- prep: W1T cast + W2T cast + hist/rank ----------------
__global__ __launch_bounds__(256) void prep_k(const float* __restrict__ W1, unsigned short* __restrict__ W1T,
                                              const float* __restrict__ W2, unsigned short* __restrict__ W2T,
                                              const int* __restrict__ edge, int* __restrict__ cnt,
                                              int* __restrict__ rank, int E) {
    int b = blockIdx.x;
    if (b < 256) {
        int i = b * 256 + threadIdx.x;
        int k = i >> 8, n = i & 255;
        W1T[(size_t)n * 256 + k] = f2bf(W1[i]);
    } else if (b < 320) {
        int i = (b - 256) * 256 + threadIdx.x;
        int k = i >> 6, n = i & 63;
        W2T[(size_t)n * 256 + k] = f2bf(W2[i]);
    } else {
        int i = (b - 320) * 256 + threadIdx.x;
        if (i < E) rank[i] = atomicAdd(&cnt[edge[E + i]], 1);
    }
}

// ---------------- scan hierarchy ----------------
__global__ __launch_bounds__(256) void psum_k(const int* __restrict__ cnt, int* __restrict__ bsum, int N) {
    __shared__ int wsh[4];
    int b = blockIdx.x;
    int gi = b * 1024 + threadIdx.x * 4;
    int s = 0;
    if (gi + 3 < N) {
        int4 v = *(const int4*)(cnt + gi);
        s = v.x + v.y + v.z + v.w + 4;
    } else {
        for (int j = 0; j < 4; ++j) if (gi + j < N) s += cnt[gi + j] + 1;
    }
#pragma unroll
    for (int off = 1; off < 64; off <<= 1) s += __shfl_xor(s, off, 64);
    if ((threadIdx.x & 63) == 0) wsh[threadIdx.x >> 6] = s;
    __syncthreads();
    if (threadIdx.x == 0) bsum[b] = wsh[0] + wsh[1] + wsh[2] + wsh[3];
}

__global__ void bscan_k(int* __restrict__ bsum, int B) {
    __shared__ int sh[128];
    int t = threadIdx.x;
    int v = (t < B) ? bsum[t] : 0;
    sh[t] = v;
    __syncthreads();
    for (int off = 1; off < 128; off <<= 1) {
        int u = (t >= off) ? sh[t - off] : 0;
        __syncthreads();
        sh[t] += u;
        __syncthreads();
    }
    if (t < B) bsum[t] = sh[t] - v;  // exclusive prefix
}

__global__ __launch_bounds__(256) void rowptr_k(const int* __restrict__ cnt, const int* __restrict__ bsum,
                                                int* __restrict__ row_ptr, int N) {
    __shared__ int wsh[4];
    int b = blockIdx.x;
    int t = threadIdx.x;
    int gi = b * 1024 + t * 4;
    int c[4];
    int s = 0;
#pragma unroll
    for (int j = 0; j < 4; ++j) {
        int i = gi + j;
        c[j] = (i < N) ? cnt[i] + 1 : 0;
        s += c[j];
    }
    int lane = t & 63, w = t >> 6;
    int ps = s;
#pragma unroll
    for (int off = 1; off < 64; off <<= 1) {
        int u = __shfl_up(ps, off, 64);
        if (lane >= off) ps += u;
    }
    if (lane == 63) wsh[w] = ps;
    __syncthreads();
    int wbase = 0;
    for (int k = 0; k < w; ++k) wbase += wsh[k];
    int base = bsum[b] + wbase + (ps - s);
#pragma unroll
    for (int j = 0; j < 4; ++j) {
        int i = gi + j;
        if (i < N) row_ptr[i] = base;
        base += c[j];
    }
    if (N - 1 >= gi && N - 1 < gi + 4) row_ptr[N] = base;
}

// ---------------- counting-sort placement (no atomics) ----------------
__global__ void scatter_k(const int* __restrict__ edge, const int* __restrict__ row_ptr,
                          const int* __restrict__ rank, int* __restrict__ col, int E, int N) {
    int i = blockIdx.x * blockDim.x + threadIdx.x;
    if (i < E) {
        int dst = edge[E + i];
        col[row_ptr[dst] + rank[i]] = edge[i];
    } else if (i < E + N) {
        int n = i - E;
        col[row_ptr[n + 1] - 1] = n;    // self-loop in last slot
    }
}

// ---------------- gemm1: fp8 Q = f32 A @ BT^T (cast fused, no bf16 out) ----------------
__global__ __launch_bounds__(256) void gemm1f_k(const float* __restrict__ A,
                                                const unsigned short* __restrict__ BT,
                                                unsigned char* __restrict__ Q, int M) {
    constexpr int K = 256, BM = 128, BK = 32;
    __shared__ char As[BM * 80];
    __shared__ char Bs[256 * 80];
    int tid = threadIdx.x;
    int m0 = blockIdx.x * BM;
    int wid = tid >> 6, lane = tid & 63;
    int wm = (wid >> 1) * 64, wn = (wid & 1) * 128;
    int l15 = lane & 15, g = lane >> 4;
    f32x4 acc[4][8] = {};

    for (int k0 = 0; k0 < K; k0 += BK) {
#pragma unroll
        for (int i = 0; i < 2; ++i) {
            int c = tid + i * 256;
            int r = c >> 2, kc = c & 3;
            int gm = m0 + r; if (gm >= M) gm = M - 1;
            const float* src = A + (size_t)gm * K + k0 + kc * 8;
            float4 v0 = *(const float4*)(src);
            float4 v1 = *(const float4*)(src + 4);
            uint4 pk;
            pk.x = f2bf(v0.x) | ((unsigned)f2bf(v0.y) << 16);
            pk.y = f2bf(v0.z) | ((unsigned)f2bf(v0.w) << 16);
            pk.z = f2bf(v1.x) | ((unsigned)f2bf(v1.y) << 16);
            pk.w = f2bf(v1.z) | ((unsigned)f2bf(v1.w) << 16);
            *(uint4*)(As + r * 80 + kc * 16) = pk;
        }
#pragma unroll
        for (int i = 0; i < 4; ++i) {
            int c = tid + i * 256;
            int r = c >> 2, kc = c & 3;
            float4 v = *(const float4*)(BT + (size_t)r * K + k0 + kc * 8);
            *(float4*)(Bs + r * 80 + kc * 16) = v;
        }
        __syncthreads();
        bf16x8 af[4], bfr[8];
#pragma unroll
        for (int i = 0; i < 4; ++i)
            af[i] = *(const bf16x8*)(As + (wm + i * 16 + l15) * 80 + g * 16);
#pragma unroll
        for (int j = 0; j < 8; ++j)
            bfr[j] = *(const bf16x8*)(Bs + (wn + j * 16 + l15) * 80 + g * 16);
#pragma unroll
        for (int i = 0; i < 4; ++i)
#pragma unroll
            for (int j = 0; j < 8; ++j)
                acc[i][j] = __builtin_amdgcn_mfma_f32_16x16x32_bf16(af[i], bfr[j], acc[i][j], 0, 0, 0);
        __syncthreads();
    }
#pragma unroll
    for (int i = 0; i < 4; ++i)
#pragma unroll
        for (int j = 0; j < 8; ++j) {
            int col = wn + j * 16 + l15;
            int gmb = m0 + wm + i * 16 + g * 4;
            int p01 = __builtin_amdgcn_cvt_pk_fp8_f32(acc[i][j][0], acc[i][j][1], 0, false);
            int p23 = __builtin_amdgcn_cvt_pk_fp8_f32(acc[i][j][2], acc[i][j][3], 0, false);
#pragma unroll
            for (int r = 0; r < 4; ++r) {
                int gm = gmb + r;
                if (gm < M) {
                    int pk = (r < 2) ? p01 : p23;
                    Q[(size_t)gm * 256 + col] = (unsigned char)((pk >> ((r & 1) * 8)) & 0xff);
                }
            }
        }
}

// ---------------- gemm2: fp8 Q2 = bf16 A @ BT^T ----------------
__global__ __launch_bounds__(256) void gemm2_k(const unsigned short* __restrict__ A,
                                               const unsigned short* __restrict__ BT,
                                               unsigned char* __restrict__ Q2, int M) {
    constexpr int N = 64, K = 256, BM = 128, BK = 32, BN = 64;
    __shared__ char As[BM * 80];
    __shared__ char Bs[BN * 80];
    int tid = threadIdx.x;
    int m0 = blockIdx.x * BM;
    int wid = tid >> 6, lane = tid & 63;
    int wm = (wid >> 1) * 64, wn = (wid & 1) * 32;
    int l15 = lane & 15, g = lane >> 4;
    f32x4 acc[4][2] = {};

    for (int k0 = 0; k0 < K; k0 += BK) {
#pragma unroll
        for (int i = 0; i < 2; ++i) {
            int c = tid + i * 256;
            int r = c >> 2, kc = c & 3;
            int gm = m0 + r; if (gm >= M) gm = M - 1;
            float4 v = *(const float4*)(A + (size_t)gm * K + k0 + kc * 8);
            *(float4*)(As + r * 80 + kc * 16) = v;
        }
        {
            int c = tid;
            int r = c >> 2, kc = c & 3;
            float4 v = *(const float4*)(BT + (size_t)r * K + k0 + kc * 8);
            *(float4*)(Bs + r * 80 + kc * 16) = v;
        }
        __syncthreads();
        bf16x8 af[4], bfr[2];
#pragma unroll
        for (int i = 0; i < 4; ++i)
            af[i] = *(const bf16x8*)(As + (wm + i * 16 + l15) * 80 + g * 16);
#pragma unroll
        for (int j = 0; j < 2; ++j)
            bfr[j] = *(const bf16x8*)(Bs + (wn + j * 16 + l15) * 80 + g * 16);
#pragma unroll
        for (int i = 0; i < 4; ++i)
#pragma unroll
            for (int j = 0; j < 2; ++j)
                acc[i][j] = __builtin_amdgcn_mfma_f32_16x16x32_bf16(af[i], bfr[j], acc[i][j], 0, 0, 0);
        __syncthreads();
    }
#pragma unroll
    for (int i = 0; i < 4; ++i)
#pragma unroll
        for (int j = 0; j < 2; ++j) {
            int col = wn + j * 16 + l15;
            int gmb = m0 + wm + i * 16 + g * 4;
            int p01 = __builtin_amdgcn_cvt_pk_fp8_f32(acc[i][j][0], acc[i][j][1], 0, false);
            int p23 = __builtin_amdgcn_cvt_pk_fp8_f32(acc[i][j][2], acc[i][j][3], 0, false);
#pragma unroll
            for (int r = 0; r < 4; ++r) {
                int gm = gmb + r;
                if (gm < M) {
                    int pk = (r < 2) ? p01 : p23;
                    Q2[(size_t)gm * N + col] = (unsigned char)((pk >> ((r & 1) * 8)) & 0xff);
                }
            }
        }
}

// ---------------- attention logits: dots1 reads fp8 ----------------
__global__ void dots1_k(const unsigned char* __restrict__ xq, const float* __restrict__ as_,
                        const float* __restrict__ ad_, float* __restrict__ es,
                        float* __restrict__ ed, int N8) {
    __shared__ float ws[256], wd[256];
    ws[threadIdx.x] = as_[threadIdx.x];
    wd[threadIdx.x] = ad_[threadIdx.x];
    __syncthreads();
    int idx = blockIdx.x * 256 + threadIdx.x;
    if (idx >= N8) return;
    int n = idx >> 3, hh = idx & 7;
    const uint4* p = (const uint4*)(xq + (size_t)n * 256 + hh * 32);
    const float* s = ws + hh * 32;
    const float* d = wd + hh * 32;
    float a = 0.f, b = 0.f;
#pragma unroll
    for (int j = 0; j < 2; ++j) {
        uint4 v = p[j];
        unsigned dws[4] = {v.x, v.y, v.z, v.w};
#pragma unroll
        for (int k = 0; k < 4; ++k) {
            int c0 = j * 16 + k * 4;
            f32x2 lo = __builtin_amdgcn_cvt_pk_f32_fp8(dws[k], false);
            f32x2 hi = __builtin_amdgcn_cvt_pk_f32_fp8(dws[k], true);
            a += lo[0] * s[c0] + lo[1] * s[c0 + 1] + hi[0] * s[c0 + 2] + hi[1] * s[c0 + 3];
            b += lo[0] * d[c0] + lo[1] * d[c0 + 1] + hi[0] * d[c0 + 2] + hi[1] * d[c0 + 3];
        }
    }
    es[idx] = a;
    ed[idx] = b;
}

// ---------------- dots2 reads fp8 ----------------
__global__ void dots2_k(const unsigned char* __restrict__ xq2, const float* __restrict__ as_,
                        const float* __restrict__ ad_, float* __restrict__ es,
                        float* __restrict__ ed, int N) {
    __shared__ float ws[64], wd[64];
    if (threadIdx.x < 64) { ws[threadIdx.x] = as_[threadIdx.x]; wd[threadIdx.x] = ad_[threadIdx.x]; }
    __syncthreads();
    int n = blockIdx.x * blockDim.x + threadIdx.x;
    if (n >= N) return;
    const uint4* p = (const uint4*)(xq2 + (size_t)n * 64);
    float a = 0.f, b = 0.f;
#pragma unroll
    for (int j = 0; j < 4; ++j) {
        uint4 v = p[j];
        unsigned dws[4] = {v.x, v.y, v.z, v.w};
#pragma unroll
        for (int k = 0; k < 4; ++k) {
            int c0 = j * 16 + k * 4;
            f32x2 lo = __builtin_amdgcn_cvt_pk_f32_fp8(dws[k], false);
            f32x2 hi = __builtin_amdgcn_cvt_pk_f32_fp8(dws[k], true);
            a += lo[0] * ws[c0] + lo[1] * ws[c0 + 1] + hi[0] * ws[c0 + 2] + hi[1] * ws[c0 + 3];
            b += lo[0] * wd[c0] + lo[1] * wd[c0 + 1] + hi[0] * wd[c0 + 2] + hi[1] * wd[c0 + 3];
        }
    }
    es[n] = a;
    ed[n] = b;
}

// ---------------- fused layer-1 aggregation: fp8 gather (R12 best: 3-buf, 32-bit addr) ----------------
__global__ __launch_bounds__(256) void agg1_k(const unsigned char* __restrict__ xq,
                                              const float* __restrict__ es, const float* __restrict__ ed,
                                              const int* __restrict__ row_ptr, const int* __restrict__ col,
                                              const float* __restrict__ bias, const float* __restrict__ gam,
                                              const float* __restrict__ bet,
                                              unsigned short* __restrict__ hout, int N) {
    int tid = threadIdx.x, wid = tid >> 6, lane = tid & 63;
    int node = blockIdx.x * 4 + wid;
    if (node >= N) return;
    int half = lane >> 5, li = lane & 31;
    unsigned hh = (unsigned)(li >> 2);
    unsigned lib = (unsigned)(li * 8);
    int start = row_ptr[node];
    int deg = row_ptr[node + 1] - start;
    float edh = ed[((unsigned)node << 3) + hh];
    f32x2 acc2[4] = {};
    float wsum = 0.f;

    float esA = 0.f, esB = 0.f, esC = 0.f;
    uint2 xA = {0, 0}, xB = {0, 0}, xC = {0, 0};
    int e = half;
    if (e < deg) { unsigned src = (unsigned)col[start + e];
        esA = es[(src << 3) + hh]; xA = *(const uint2*)(xq + ((src << 8) | lib)); }
    if (e + 2 < deg) { unsigned src = (unsigned)col[start + e + 2];
        esB = es[(src << 3) + hh]; xB = *(const uint2*)(xq + ((src << 8) | lib)); }
    if (e + 4 < deg) { unsigned src = (unsigned)col[start + e + 4];
        esC = es[(src << 3) + hh]; xC = *(const uint2*)(xq + ((src << 8) | lib)); }

#define AGG1_STEP(ESB, XB)                                                        \
    {                                                                             \
        float wgt = __expf(LRELU(ESB + edh));                                     \
        wsum += wgt;                                                              \
        f32x2 w2 = {wgt, wgt};                                                    \
        acc2[0] += w2 * __builtin_amdgcn_cvt_pk_f32_fp8(XB.x, false);             \
        acc2[1] += w2 * __builtin_amdgcn_cvt_pk_f32_fp8(XB.x, true);              \
        acc2[2] += w2 * __builtin_amdgcn_cvt_pk_f32_fp8(XB.y, false);             \
        acc2[3] += w2 * __builtin_amdgcn_cvt_pk_f32_fp8(XB.y, true);              \
        if (e + 6 < deg) {                                                        \
            unsigned src = (unsigned)col[start + e + 6];                          \
            ESB = es[(src << 3) + hh];                                            \
            XB = *(const uint2*)(xq + ((src << 8) | lib));                        \
        }                                                                         \
        e += 2;                                                                   \
    }

    if (e < deg) {
        for (;;) {
            AGG1_STEP(esA, xA);
            if (e >= deg) break;
            AGG1_STEP(esB, xB);
            if (e >= deg) break;
            AGG1_STEP(esC, xC);
            if (e >= deg) break;
        }
    }
#undef AGG1_STEP

    float a8[8];
#pragma unroll
    for (int k = 0; k < 4; ++k) { a8[2 * k] = acc2[k][0]; a8[2 * k + 1] = acc2[k][1]; }
#pragma unroll
    for (int j = 0; j < 8; ++j) a8[j] += __shfl_xor(a8[j], 32, 64);
    wsum += __shfl_xor(wsum, 32, 64);
    float inv = 1.f / wsum;
    float4 bA = *(const float4*)(bias + li * 8);
    float4 bB = *(const float4*)(bias + li * 8 + 4);
    float v[8];
    v[0] = a8[0] * inv + bA.x; v[1] = a8[1] * inv + bA.y;
    v[2] = a8[2] * inv + bA.z; v[3] = a8[3] * inv + bA.w;
    v[4] = a8[4] * inv + bB.x; v[5] = a8[5] * inv + bB.y;
    v[6] = a8[6] * inv + bB.z; v[7] = a8[7] * inv + bB.w;
    float s = 0.f, q = 0.f;
#pragma unroll
    for (int j = 0; j < 8; ++j) { s += v[j]; q += v[j] * v[j]; }
#pragma unroll
    for (int off = 1; off < 32; off <<= 1) { s += __shfl_xor(s, off, 64); q += __shfl_xor(q, off, 64); }
    float mu = s * (1.f / 256.f);
    float var = q * (1.f / 256.f) - mu * mu;
    float rs = rsqrtf(var + 1e-5f);
    float4 gA = *(const float4*)(gam + li * 8);
    float4 gB = *(const float4*)(gam + li * 8 + 4);
    float4 eA = *(const float4*)(bet + li * 8);
    float4 eB = *(const float4*)(bet + li * 8 + 4);
    float o0 = fmaxf((v[0] - mu) * rs * gA.x + eA.x, 0.f);
    float o1 = fmaxf((v[1] - mu) * rs * gA.y + eA.y, 0.f);
    float o2 = fmaxf((v[2] - mu) * rs * gA.z + eA.z, 0.f);
    float o3 = fmaxf((v[3] - mu) * rs * gA.w + eA.w, 0.f);
    float o4 = fmaxf((v[4] - mu) * rs * gB.x + eB.x, 0.f);
    float o5 = fmaxf((v[5] - mu) * rs * gB.y + eB.y, 0.f);
    float o6 = fmaxf((v[6] - mu) * rs * gB.z + eB.z, 0.f);
    float o7 = fmaxf((v[7] - mu) * rs * gB.w + eB.w, 0.f);
    if (half == 0) {
        uint4 pk;
        pk.x = f2bf(o0) | ((unsigned)f2bf(o1) << 16);
        pk.y = f2bf(o2) | ((unsigned)f2bf(o3) << 16);
        pk.z = f2bf(o4) | ((unsigned)f2bf(o5) << 16);
        pk.w = f2bf(o6) | ((unsigned)f2bf(o7) << 16);
        *(uint4*)(hout + (size_t)node * 256 + li * 8) = pk;
    }
}

// ---------------- fused layer-2 aggregation: fp8 gather ----------------
__global__ __launch_bounds__(256) void agg2_k(const unsigned char* __restrict__ xq2,
                                              const float* __restrict__ es, const float* __restrict__ ed,
                                              const int* __restrict__ row_ptr, const int* __restrict__ col,
                                              const float* __restrict__ bias, const float* __restrict__ gam,
                                              const float* __restrict__ bet,
                                              float* __restrict__ out, int N) {
    int tid = threadIdx.x, wid = tid >> 6, lane = tid & 63;
    int node = blockIdx.x * 4 + wid;
    if (node >= N) return;
    int g = lane >> 3, li = lane & 7;
    unsigned lib = (unsigned)(li * 8);
    int start = row_ptr[node];
    int deg = row_ptr[node + 1] - start;
    float edh = ed[node];
    f32x2 acc2[4] = {};
    float wsum = 0.f;

    float esA = 0.f, esB = 0.f, esC = 0.f;
    uint2 xA = {0, 0}, xB = {0, 0}, xC = {0, 0};
    int e = g;
    if (e < deg) { unsigned src = (unsigned)col[start + e];
        esA = es[src]; xA = *(const uint2*)(xq2 + ((src << 6) | lib)); }
    if (e + 8 < deg) { unsigned src = (unsigned)col[start + e + 8];
        esB = es[src]; xB = *(const uint2*)(xq2 + ((src << 6) | lib)); }
    if (e + 16 < deg) { unsigned src = (unsigned)col[start + e + 16];
        esC = es[src]; xC = *(const uint2*)(xq2 + ((src << 6) | lib)); }

#define AGG2_STEP(ESB, XB)                                                        \
    {                                                                             \
        float wgt = __expf(LRELU(ESB + edh));                                     \
        wsum += wgt;                                                              \
        f32x2 w2 = {wgt, wgt};                                                    \
        acc2[0] += w2 * __builtin_amdgcn_cvt_pk_f32_fp8(XB.x, false);             \
        acc2[1] += w2 * __builtin_amdgcn_cvt_pk_f32_fp8(XB.x, true);              \
        acc2[2] += w2 * __builtin_amdgcn_cvt_pk_f32_fp8(XB.y, false);             \
        acc2[3] += w2 * __builtin_amdgcn_cvt_pk_f32_fp8(XB.y, true);              \
        if (e + 24 < deg) {                                                       \
            unsigned src = (unsigned)col[start + e + 24];                         \
            ESB = es[src];                                                        \
            XB = *(const uint2*)(xq2 + ((src << 6) | lib));                       \
        }                                                                         \
        e += 8;                                                                   \
    }

    if (e < deg) {
        for (;;) {
            AGG2_STEP(esA, xA);
            if (e >= deg) break;
            AGG2_STEP(esB, xB);
            if (e >= deg) break;
            AGG2_STEP(esC, xC);
            if (e >= deg) break;
        }
    }
#undef AGG2_STEP

    float a8[8];
#pragma unroll
    for (int k = 0; k < 4; ++k) { a8[2 * k] = acc2[k][0]; a8[2 * k + 1] = acc2[k][1]; }
#pragma unroll
    for (int off = 8; off < 64; off <<= 1) {
#pragma unroll
        for (int j = 0; j < 8; ++j) a8[j] += __shfl_xor(a8[j], off, 64);
        wsum += __shfl_xor(wsum, off, 64);
    }
    int c = li * 8;
    float inv = 1.f / wsum;
    float v[8];
#pragma unroll
    for (int j = 0; j < 8; ++j) v[j] = a8[j] * inv + bias[c + j];
    float s = 0.f, q = 0.f;
#pragma unroll
    for (int j = 0; j < 8; ++j) { s += v[j]; q += v[j] * v[j]; }
#pragma unroll
    for (int off = 1; off < 8; off <<= 1) { s += __shfl_xor(s, off, 64); q += __shfl_xor(q, off, 64); }
    float mu = s * (1.f / 64.f);
    float var = q * (1.f / 64.f) - mu * mu;
    float rs = rsqrtf(var + 1e-5f);
    float o[8];
    float mx = -1e30f;
#pragma unroll
    for (int j = 0; j < 8; ++j) {
        o[j] = (v[j] - mu) * rs * gam[c + j] + bet[c + j];
        mx = fmaxf(mx, o[j]);
    }
#pragma unroll
    for (int off = 1; off < 8; off <<= 1) mx = fmaxf(mx, __shfl_xor(mx, off, 64));
    float se = 0.f;
#pragma unroll
    for (int j = 0; j < 8; ++j) se += __expf(o[j] - mx);
#pragma unroll
    for (int off = 1; off < 8; off <<= 1) se += __shfl_xor(se, off, 64);
    float lse = mx + logf(se);
    if (g == 0) {
        float4 o0 = make_float4(o[0] - lse, o[1] - lse, o[2] - lse, o[3] - lse);
        float4 o1 = make_float4(o[4] - lse, o[5] - lse, o[6] - lse, o[7] - lse);
        *(float4*)(out + (size_t)node * 64 + c) = o0;
        *(float4*)(out + (size_t)node * 64 + c + 4) = o1;
    }
}

extern "C" void kernel_launch(void* const* d_in, const int* in_sizes, int n_in,
                              void* d_out, int out_size, void* d_ws, size_t ws_size,
                              hipStream_t stream) {
    const float* x   = (const float*)d_in[0];
    const int*   edge = (const int*)d_in[1];
    const float* W1  = (const float*)d_in[2];
    const float* as1 = (const float*)d_in[3];
    const float* ad1 = (const float*)d_in[4];
    const float* b1  = (const float*)d_in[5];
    const float* g1  = (const float*)d_in[6];
    const float* be1 = (const float*)d_in[7];
    const float* W2  = (const float*)d_in[8];
    const float* as2 = (const float*)d_in[9];
    const float* ad2 = (const float*)d_in[10];
    const float* b2  = (const float*)d_in[11];
    const float* g2  = (const float*)d_in[12];
    const float* be2 = (const float*)d_in[13];

    int NN = in_sizes[0] / 256;
    int E  = in_sizes[1] / 2;
    int ET = E + NN;

    char* w = (char*)d_ws;
    size_t off = 0;
    auto nxt = [&](size_t b) -> void* {
        void* p = w + off;
        off = (off + b + 255) & ~(size_t)255;
        return p;
    };
    unsigned short* W1T  = (unsigned short*)nxt(256 * 256 * 2);
    unsigned short* W2T  = (unsigned short*)nxt(64 * 256 * 2);
    unsigned char*  xq   = (unsigned char*)nxt((size_t)NN * 256);
    unsigned short* hbuf = (unsigned short*)nxt((size_t)NN * 256 * 2);
    unsigned char*  xq2  = (unsigned char*)nxt((size_t)NN * 64);
    float* es1   = (float*)nxt((size_t)NN * 8 * 4);
    float* ed1   = (float*)nxt((size_t)NN * 8 * 4);
    float* es2   = (float*)nxt((size_t)NN * 4);
    float* ed2   = (float*)nxt((size_t)NN * 4);
    int* row_ptr = (int*)nxt((size_t)(NN + 1) * 4);
    int* tmpN    = (int*)nxt((size_t)NN * 4);
    int* rank    = (int*)nxt((size_t)E * 4);
    int* col     = (int*)nxt((size_t)ET * 4);
    int* bsum    = (int*)nxt(1024 * 4);
    (void)ws_size; (void)n_in; (void)out_size;

    int NB = (NN + 1023) / 1024;

    // CSR build
    (void)hipMemsetAsync(tmpN, 0, (size_t)NN * 4, stream);
    prep_k<<<320 + (E + 255) / 256, 256, 0, stream>>>(W1, W1T, W2, W2T, edge, tmpN, rank, E);
    psum_k<<<NB, 256, 0, stream>>>(tmpN, bsum, NN);
    bscan_k<<<1, 128, 0, stream>>>(bsum, NB);
    rowptr_k<<<NB, 256, 0, stream>>>(tmpN, bsum, row_ptr, NN);
    scatter_k<<<(ET + 255) / 256, 256, 0, stream>>>(edge, row_ptr, rank, col, E, NN);

    // Layer 1
    gemm1f_k<<<(NN + 127) / 128, 256, 0, stream>>>(x, W1T, xq, NN);
    dots1_k<<<(NN * 8 + 255) / 256, 256, 0, stream>>>(xq, as1, ad1, es1, ed1, NN * 8);
    agg1_k<<<(NN + 3) / 4, 256, 0, stream>>>(xq, es1, ed1, row_ptr, col, b1, g1, be1, hbuf, NN);

    // Layer 2
    gemm2_k<<<(NN + 127) / 128, 256, 0, stream>>>(hbuf, W2T, xq2, NN);
    dots2_k<<<(NN + 255) / 256, 256, 0, stream>>>(xq2, as2, ad2, es2, ed2, NN);
    agg2_k<<<(NN + 3) / 4, 256, 0, stream>>>(xq2, es2, ed2, row_ptr, col, b2, g2, be2,
                                             (float*)d_out, NN);
}